// Round 4
// baseline (1053.872 us; speedup 1.0000x reference)
//
#include <hip/hip_runtime.h>
#include <hip/hip_bf16.h>
#include <cstdint>

// ---------------- problem constants ----------------
// B=2, S=2048, D=2048, H=16, HD=128, FF=8192; M = B*S = 4096 rows
constexpr float SCALE_QK = 0.02209708691207961f; // 1/sqrt(2048)  (ref uses 1/sqrt(D))

using short8 = __attribute__((ext_vector_type(8))) short;
using f32x4  = __attribute__((ext_vector_type(4))) float;

#define MFMA16(a,b,c) __builtin_amdgcn_mfma_f32_16x16x32_bf16((a),(b),(c),0,0,0)

__device__ __forceinline__ ushort f2bf(float f){
  uint32_t u = __builtin_bit_cast(uint32_t, f);
  u += 0x7fffu + ((u >> 16) & 1u);      // RNE
  return (ushort)(u >> 16);
}

// async global->LDS, 16B per lane; LDS dest is wave-uniform base + lane*16
__device__ __forceinline__ void gload_lds16(const void* g, void* l){
  __builtin_amdgcn_global_load_lds(
      (const __attribute__((address_space(1))) void*)g,
      (__attribute__((address_space(3))) void*)l, 16, 0, 0);
}

// ---------------- LayerNorm: fp32 row -> bf16 row ----------------
__global__ __launch_bounds__(256) void ln_kernel(
    const float* __restrict__ x, const float* __restrict__ g,
    const float* __restrict__ sh, ushort* __restrict__ out){
  const int row = blockIdx.x, t = threadIdx.x;
  const float* xr = x + (size_t)row*2048 + t*8;
  float v[8];
  *(float4*)&v[0] = *(const float4*)(xr);
  *(float4*)&v[4] = *(const float4*)(xr + 4);
  float s = 0.f, sq = 0.f;
#pragma unroll
  for (int i = 0; i < 8; ++i){ s += v[i]; sq += v[i]*v[i]; }
#pragma unroll
  for (int d = 1; d < 64; d <<= 1){ s += __shfl_xor(s, d, 64); sq += __shfl_xor(sq, d, 64); }
  __shared__ float red[8];
  const int w = t >> 6, lane = t & 63;
  if (lane == 0){ red[w] = s; red[4 + w] = sq; }
  __syncthreads();
  s  = red[0] + red[1] + red[2] + red[3];
  sq = red[4] + red[5] + red[6] + red[7];
  const float mean = s * (1.f/2048.f);
  const float inv  = rsqrtf(sq * (1.f/2048.f) - mean*mean + 1e-5f);
  union { ushort u[8]; uint4 v4; } o;
#pragma unroll
  for (int i = 0; i < 8; ++i){
    int j = t*8 + i;
    o.u[i] = f2bf((v[i] - mean) * inv * g[j] + sh[j]);
  }
  *(uint4*)(out + (size_t)row*2048 + t*8) = o.v4;
}

// ---------------- weight convert + transpose: fp32 [K][N] -> bf16 [N][K] ----------------
__global__ __launch_bounds__(256) void wconv_t(
    const float* __restrict__ in, ushort* __restrict__ out, int K, int N){
  __shared__ ushort tile[32][34];
  const int tx = threadIdx.x & 31, ty = threadIdx.x >> 5;
  const int n0 = blockIdx.x * 32, k0 = blockIdx.y * 32;
#pragma unroll
  for (int r = 0; r < 4; ++r){
    int kk = ty + r*8;
    tile[kk][tx] = f2bf(in[(size_t)(k0 + kk)*N + n0 + tx]);
  }
  __syncthreads();
#pragma unroll
  for (int r = 0; r < 4; ++r){
    int nn = ty + r*8;
    out[(size_t)(n0 + nn)*K + k0 + tx] = tile[tx][nn];
  }
}

// ---------------- V transpose: bf16 [bh][s][128] -> [bh][128][s] ----------------
__global__ __launch_bounds__(256) void vtrans(
    const ushort* __restrict__ v, ushort* __restrict__ vt){
  __shared__ ushort tile[32][34];
  const int tx = threadIdx.x & 31, ty = threadIdx.x >> 5;
  const int d0 = blockIdx.x * 32, s0 = blockIdx.y * 32, bh = blockIdx.z;
  const ushort* vb = v  + (size_t)bh * 2048 * 128;
  ushort* vtb      = vt + (size_t)bh * 128 * 2048;
#pragma unroll
  for (int r = 0; r < 4; ++r){
    int ss = ty + r*8;
    tile[ss][tx] = vb[(size_t)(s0 + ss)*128 + d0 + tx];
  }
  __syncthreads();
#pragma unroll
  for (int r = 0; r < 4; ++r){
    int dd = ty + r*8;
    vtb[(size_t)(d0 + dd)*2048 + s0 + tx] = tile[tx][dd];
  }
}

// ================= 256x256 8-wave 4-phase GEMM (T3+T4+T5) =================
// C[4096,N] = A[4096,K] * Bt[N,K]^T, bf16 in, fp32 acc.
// 512 thr = 8 waves (2M x 4N); wave output 128x64 = acc[8][4] frags.
// LDS: A,B each [2 dbuf][2 half(128 rows)][128*64] bf16 = 128 KiB total.
// Per K-tile: 4 phases x {ds_read quad, stage 1 half-tile (2 gload_lds),
// barrier, 16 MFMA in setprio}. Staging order A0l0,A1l0,B0l0,B0l1,B1l0,B1l1,
// A0l1,A1l1 => phase0 needs oldest 6 (vmcnt(2)); phase2 needs A*l1 (vmcnt(4)
// steady / vmcnt(0) last tile). Never drains in steady loop.
// EPI 0: fused-QKV scatter bf16; EPI 2: gelu(acc+bias) -> bf16.
#define QUAD(p) { \
  short8 af[2][2]; \
  _Pragma("unroll") for (int ii = 0; ii < 2; ++ii) \
  _Pragma("unroll") for (int kk = 0; kk < 2; ++kk){ \
    const int r = (2*(p)+ii)*16 + l15; \
    af[ii][kk] = *(const short8*)&Alds[cur][wr][r*64 + (((kk*4 + l4) ^ (r & 7))*8)]; } \
  __builtin_amdgcn_s_setprio(1); \
  _Pragma("unroll") for (int ii = 0; ii < 2; ++ii) \
  _Pragma("unroll") for (int ni = 0; ni < 4; ++ni) \
  _Pragma("unroll") for (int kk = 0; kk < 2; ++kk) \
    acc[2*(p)+ii][ni] = MFMA16(af[ii][kk], bfr[ni][kk], acc[2*(p)+ii][ni]); \
  __builtin_amdgcn_s_setprio(0); }

template<int EPI>
__global__ __launch_bounds__(512, 2) void gemm256(
    const ushort* __restrict__ A, const ushort* __restrict__ Bt,
    int N, int K, void* __restrict__ outp, const float* __restrict__ bias){
  __shared__ ushort Alds[2][2][128*64];   // 64 KiB
  __shared__ ushort Blds[2][2][128*64];   // 64 KiB
  const int tid = threadIdx.x, lane = tid & 63, wid = tid >> 6;
  const int wr = wid >> 2, wc = wid & 3;
  const int l15 = lane & 15, l4 = lane >> 4;

  // XCD remap: 16 m-tiles = 8 XCD x 2; consecutive j share 2 A-panels (L2-fit)
  const int bid = blockIdx.x;
  const int xcd = bid & 7, j = bid >> 3;
  const int m0 = (xcd*2 + (j & 1)) * 256;
  const int n0 = (j >> 1) * 256;

  const ushort* Abase = A  + (size_t)m0*K;
  const ushort* Bbase = Bt + (size_t)n0*K;

  f32x4 acc[8][4];
#pragma unroll
  for (int mi = 0; mi < 8; ++mi)
#pragma unroll
    for (int ni = 0; ni < 4; ++ni) acc[mi][ni] = (f32x4){0.f,0.f,0.f,0.f};

  // stage: half h (rows h*128..+127), load l (rows l*64..+63), K-tile kt2
  auto stageA = [&](int buf, int h, int l, int kt2){
    const int c = l*512 + tid;                 // 16B chunk id in half
    const int r = c >> 3, s = c & 7;
    gload_lds16(Abase + (size_t)(h*128 + r)*K + (size_t)kt2*64 + ((s ^ (r & 7))*8),
                &Alds[buf][h][c*8]);
  };
  auto stageB = [&](int buf, int h, int l, int kt2){
    const int c = l*512 + tid;
    const int r = c >> 3, s = c & 7;
    gload_lds16(Bbase + (size_t)(h*128 + r)*K + (size_t)kt2*64 + ((s ^ (r & 7))*8),
                &Blds[buf][h][c*8]);
  };

  const int NTk = K >> 6;
  // prologue: stage tile 0, canonical order
  stageA(0,0,0,0); stageA(0,1,0,0);
  stageB(0,0,0,0); stageB(0,0,1,0);
  stageB(0,1,0,0); stageB(0,1,1,0);
  stageA(0,0,1,0); stageA(0,1,1,0);

  short8 bfr[4][2];
  for (int kt = 0; kt < NTk; ++kt){
    const int cur = kt & 1, nxt = cur ^ 1;
    const bool more = (kt + 1 < NTk);
    // ---- phase 0: B all + A quad 0 ----
    asm volatile("s_waitcnt vmcnt(2)" ::: "memory");
    __builtin_amdgcn_s_barrier();
    asm volatile("" ::: "memory");
#pragma unroll
    for (int ni = 0; ni < 4; ++ni)
#pragma unroll
      for (int kk = 0; kk < 2; ++kk){
        const int rB = wc*64 + ni*16 + l15;
        const int bh = rB >> 7, r = rB & 127;
        bfr[ni][kk] = *(const short8*)&Blds[cur][bh][r*64 + (((kk*4 + l4) ^ (r & 7))*8)];
      }
    if (more){ stageA(nxt,0,0,kt+1); stageA(nxt,1,0,kt+1); }
    QUAD(0)
    // ---- phase 1 ----
    __builtin_amdgcn_s_barrier();
    asm volatile("" ::: "memory");
    if (more){ stageB(nxt,0,0,kt+1); stageB(nxt,0,1,kt+1); }
    QUAD(1)
    // ---- phase 2 (needs A rows 64-95 -> A*l1 of this tile) ----
    if (more) asm volatile("s_waitcnt vmcnt(4)" ::: "memory");
    else      asm volatile("s_waitcnt vmcnt(0)" ::: "memory");
    __builtin_amdgcn_s_barrier();
    asm volatile("" ::: "memory");
    if (more){ stageB(nxt,1,0,kt+1); stageB(nxt,1,1,kt+1); }
    QUAD(2)
    // ---- phase 3 ----
    __builtin_amdgcn_s_barrier();
    asm volatile("" ::: "memory");
    if (more){ stageA(nxt,0,1,kt+1); stageA(nxt,1,1,kt+1); }
    QUAD(3)
  }

  // epilogue
#pragma unroll
  for (int mi = 0; mi < 8; ++mi){
#pragma unroll
    for (int ni = 0; ni < 4; ++ni){
      const int rloc = wr*128 + mi*16 + l4*4;
      const int col  = n0 + wc*64 + ni*16 + l15;
#pragma unroll
      for (int j2 = 0; j2 < 4; ++j2){
        const int m = m0 + rloc + j2;
        float v = acc[mi][ni][j2];
        if constexpr (EPI == 0){            // fused QKV scatter
          const int which = col >> 11, rest = col & 2047;
          const int b = m >> 11, s = m & 2047, h = rest >> 7, d = rest & 127;
          ((ushort*)outp)[(size_t)which*8388608 +
                          (((size_t)(b*16 + h)*2048 + s) << 7) + d] = f2bf(v);
        } else {                            // gelu(acc + bias) -> bf16
          const float xx = v + bias[col];
          const float z  = 0.7978845608f*(xx + 0.044715f*xx*xx*xx);
          const float t  = __expf(-2.f*fabsf(z));
          const float th = (1.f - t)/(1.f + t);
          const float gl = 0.5f*xx*(1.f + copysignf(th, xx));
          ((ushort*)outp)[(size_t)m*N + col] = f2bf(gl);
        }
      }
    }
  }
}

// ---------------- 128x128 m97-structure GEMM (proj / FFN2) ----------------
// EPI 1: fp32 out = resid + bias + acc
template<int EPI>
__global__ __launch_bounds__(256) void gemm_bt(
    const ushort* __restrict__ A, const ushort* __restrict__ Bt,
    int N, int K, void* __restrict__ outp,
    const float* __restrict__ resid, const float* __restrict__ bias){
  __shared__ ushort lds[2][128*64];
  const int tid = threadIdx.x, lane = tid & 63, wid = tid >> 6;
  const int wr = wid >> 1, wc = wid & 1;
  const int l15 = lane & 15, l4 = lane >> 4;

  const int bid = blockIdx.x;
  const int xcd = bid & 7, j = bid >> 3;
  const int mb = xcd*4 + (j & 3);
  const int nb = j >> 2;
  const int m0 = mb * 128, n0 = nb * 128;

  f32x4 acc[4][4];
#pragma unroll
  for (int mi = 0; mi < 4; ++mi)
#pragma unroll
    for (int ni = 0; ni < 4; ++ni) acc[mi][ni] = (f32x4){0.f,0.f,0.f,0.f};

  const ushort* Abase = A  + (size_t)m0*K;
  const ushort* Bbase = Bt + (size_t)n0*K;

  const int NTk = K >> 6;
  for (int kt = 0; kt < NTk; ++kt){
    if (kt) __syncthreads();
#pragma unroll
    for (int i = 0; i < 4; ++i){
      const int chunk = (i*4 + wid)*64 + lane;
      const int row = chunk >> 3;
      const int c8  = (chunk & 7) ^ (row & 7);
      const size_t goff = (size_t)row*K + (size_t)kt*64 + c8*8;
      gload_lds16(Abase + goff, (ushort*)&lds[0][0] + (size_t)(i*4 + wid)*512);
      gload_lds16(Bbase + goff, (ushort*)&lds[1][0] + (size_t)(i*4 + wid)*512);
    }
    __syncthreads();

#pragma unroll
    for (int kk = 0; kk < 2; ++kk){
      short8 af[4], bf[4];
      const int kb = kk*4 + l4;
#pragma unroll
      for (int i = 0; i < 4; ++i){
        const int rA = wr*64 + i*16 + l15;
        af[i] = *(const short8*)&lds[0][rA*64 + ((kb ^ (rA & 7))*8)];
        const int rB = wc*64 + i*16 + l15;
        bf[i] = *(const short8*)&lds[1][rB*64 + ((kb ^ (rB & 7))*8)];
      }
#pragma unroll
      for (int mi = 0; mi < 4; ++mi)
#pragma unroll
        for (int ni = 0; ni < 4; ++ni)
          acc[mi][ni] = MFMA16(af[mi], bf[ni], acc[mi][ni]);
    }
  }

#pragma unroll
  for (int mi = 0; mi < 4; ++mi){
#pragma unroll
    for (int ni = 0; ni < 4; ++ni){
      const int rloc = wr*64 + mi*16 + l4*4;
      const int col  = n0 + wc*64 + ni*16 + l15;
#pragma unroll
      for (int j = 0; j < 4; ++j){
        const int m = m0 + rloc + j;
        float v = acc[mi][ni][j];
        if constexpr (EPI == 1){
          ((float*)outp)[(size_t)m*N + col] = resid[(size_t)m*N + col] + bias[col] + v;
        } else {
          ((ushort*)outp)[(size_t)m*N + col] = f2bf(v);
        }
      }
    }
  }
}

// ---------------- causal flash attention (unchanged from R3) ----------------
__global__ __launch_bounds__(256, 4) void attn_kernel(
    const ushort* __restrict__ q, const ushort* __restrict__ k,
    const ushort* __restrict__ vt, ushort* __restrict__ ctx){
  __shared__ ushort k_lds[2][64*128];
  __shared__ ushort p_lds[4][16*64];
  const int tid = threadIdx.x, lane = tid & 63, w = tid >> 6;
  const int l15 = lane & 15, l4 = lane >> 4;
  const int id = blockIdx.x;
  const int bh = id & 31;
  const int qt = 31 - (id >> 5);
  const int bb = bh >> 4, hh = bh & 15;
  const ushort* kbase = k  + (size_t)bh * 262144;
  const ushort* vbase = vt + (size_t)bh * 262144;

  short8 qf[4];
  {
    const int s = qt*64 + w*16 + l15;
    const ushort* qr = q + ((size_t)bh*2048 + s)*128 + l4*8;
#pragma unroll
    for (int kk = 0; kk < 4; ++kk) qf[kk] = *(const short8*)(qr + kk*32);
  }

  f32x4 cacc[8];
#pragma unroll
  for (int dt = 0; dt < 8; ++dt) cacc[dt] = (f32x4){0.f,0.f,0.f,0.f};
  float mrun[4], lrun[4];
#pragma unroll
  for (int j = 0; j < 4; ++j){ mrun[j] = -1e30f; lrun[j] = 0.f; }

  auto stage = [&](int buf, int t){
    const ushort* src = kbase + (size_t)t*8192;
#pragma unroll
    for (int i = 0; i < 4; ++i){
      const int base = i*256 + w*64;
      const int chunk = base + lane;
      const int row = chunk >> 4;
      const int c8  = (chunk & 15) ^ (row & 7);
      gload_lds16(src + (size_t)row*128 + c8*8, &k_lds[buf][(size_t)base*8]);
    }
  };

  const int nt = qt + 1;
  stage(0, 0);
  __syncthreads();
  int cur = 0;
  for (int t = 0; t < nt; ++t){
    if (t + 1 < nt) stage(cur ^ 1, t + 1);

    f32x4 sa[4];
#pragma unroll
    for (int ct = 0; ct < 4; ++ct) sa[ct] = (f32x4){0.f,0.f,0.f,0.f};
    __builtin_amdgcn_s_setprio(1);
#pragma unroll
    for (int kk = 0; kk < 4; ++kk){
#pragma unroll
      for (int ct = 0; ct < 4; ++ct){
        const int kr = ct*16 + l15;
        short8 kf = *(const short8*)&k_lds[cur][kr*128 + (((kk*4 + l4) ^ (kr & 7))*8)];
        sa[ct] = MFMA16(qf[kk], kf, sa[ct]);
      }
    }
    __builtin_amdgcn_s_setprio(0);

#pragma unroll
    for (int j = 0; j < 4; ++j){
      const int qa = qt*64 + w*16 + l4*4 + j;
      float mnew = mrun[j];
#pragma unroll
      for (int ct = 0; ct < 4; ++ct){
        float sc = sa[ct][j] * SCALE_QK;
        if (t == qt){
          const int ka = t*64 + ct*16 + l15;
          sc = (ka > qa) ? -1e30f : sc;
        }
        sa[ct][j] = sc;
        mnew = fmaxf(mnew, sc);
      }
#pragma unroll
      for (int d = 1; d < 16; d <<= 1) mnew = fmaxf(mnew, __shfl_xor(mnew, d, 16));
      const float corr = __expf(mrun[j] - mnew);
      mrun[j] = mnew; lrun[j] *= corr;
      float psum = 0.f;
#pragma unroll
      for (int ct = 0; ct < 4; ++ct){
        const float p = __expf(sa[ct][j] - mnew);
        sa[ct][j] = p; psum += p;
      }
      lrun[j] += psum;
#pragma unroll
      for (int dt = 0; dt < 8; ++dt) cacc[dt][j] *= corr;
    }

#pragma unroll
    for (int ct = 0; ct < 4; ++ct)
#pragma unroll
      for (int j = 0; j < 4; ++j){
        const int row = l4*4 + j, col = ct*16 + l15;
        p_lds[w][row*64 + ((col >> 3) ^ (row & 7))*8 + (col & 7)] = f2bf(sa[ct][j]);
      }

    const ushort* vtile = vbase + (size_t)t*64;
    __builtin_amdgcn_s_setprio(1);
#pragma unroll
    for (int kk2 = 0; kk2 < 2; ++kk2){
      short8 pa = *(const short8*)&p_lds[w][l15*64 + (((kk2*4 + l4) ^ (l15 & 7))*8)];
#pragma unroll
      for (int dt = 0; dt < 8; ++dt){
        short8 vf = *(const short8*)(vtile + (size_t)(dt*16 + l15)*2048 + (kk2*4 + l4)*8);
        cacc[dt] = MFMA16(pa, vf, cacc[dt]);
      }
    }
    __builtin_amdgcn_s_setprio(0);

    if (t + 1 < nt){ __syncthreads(); cur ^= 1; }
  }

  float inv[4];
#pragma unroll
  for (int j = 0; j < 4; ++j){
    float lt = lrun[j];
#pragma unroll
    for (int d = 1; d < 16; d <<= 1) lt += __shfl_xor(lt, d, 16);
    inv[j] = 1.f / lt;
  }
#pragma unroll
  for (int dt = 0; dt < 8; ++dt)
#pragma unroll
    for (int j = 0; j < 4; ++j){
      const int s = qt*64 + w*16 + l4*4 + j;
      const int d = dt*16 + l15;
      ctx[((size_t)(bb*2048 + s))*2048 + hh*128 + d] = f2bf(cacc[dt][j] * inv[j]);
    }
}

// ---------------- launch ----------------
extern "C" void kernel_launch(void* const* d_in, const int* in_sizes, int n_in,
                              void* d_out, int out_size, void* d_ws, size_t ws_size,
                              hipStream_t stream) {
  const float* x  = (const float*)d_in[0];
  const float* wq = (const float*)d_in[1];
  const float* wk = (const float*)d_in[2];
  const float* wv = (const float*)d_in[3];
  const float* wo = (const float*)d_in[4];
  const float* bo = (const float*)d_in[5];
  const float* g1 = (const float*)d_in[6];
  const float* s1 = (const float*)d_in[7];
  const float* g2 = (const float*)d_in[8];
  const float* s2 = (const float*)d_in[9];
  const float* w1 = (const float*)d_in[10];
  const float* b1 = (const float*)d_in[11];
  const float* w2 = (const float*)d_in[12];
  const float* b2 = (const float*)d_in[13];
  float* out = (float*)d_out;
  char* ws = (char*)d_ws;

  // workspace layout (bytes)
  ushort* wqkvT = (ushort*)(ws + 0);         // [6144][2048] bf16 (wq|wk|wv transposed)
  ushort* wkT = (ushort*)(ws + 8388608);
  ushort* wvT = (ushort*)(ws + 16777216);
  ushort* woT = (ushort*)(ws + 25165824);
  ushort* w1T = (ushort*)(ws + 33554432);    // [8192][2048]
  ushort* w2T = (ushort*)(ws + 67108864);    // [2048][8192]
  ushort* h1  = (ushort*)(ws + 100663296);   // [4096][2048]
  ushort* qb  = (ushort*)(ws + 117440512);   // [32][2048][128]; kb,vb follow contiguously
  ushort* vb  = (ushort*)(ws + 150994944);
  ushort* vtb = (ushort*)(ws + 167772160);   // [32][128][2048]
  ushort* ctxb= (ushort*)(ws + 184549376);   // [4096][2048]
  float*  x2  = (float*)(ws + 201326592);    // [4096][2048] fp32
  ushort* h2  = (ushort*)(ws + 234881024);   // [4096][2048]
  ushort* ffb = (ushort*)(ws + 117440512);   // [4096][8192] aliases q/k/v/vt (dead after attn)
  ushort* kb  = (ushort*)(ws + 134217728);

  // weights -> bf16 transposed
  wconv_t<<<dim3(64, 64), 256, 0, stream>>>(wq, wqkvT, 2048, 2048);
  wconv_t<<<dim3(64, 64), 256, 0, stream>>>(wk, wkT, 2048, 2048);
  wconv_t<<<dim3(64, 64), 256, 0, stream>>>(wv, wvT, 2048, 2048);
  wconv_t<<<dim3(64, 64), 256, 0, stream>>>(wo, woT, 2048, 2048);
  wconv_t<<<dim3(256, 64), 256, 0, stream>>>(w1, w1T, 2048, 8192);
  wconv_t<<<dim3(64, 256), 256, 0, stream>>>(w2, w2T, 8192, 2048);

  // LN1
  ln_kernel<<<4096, 256, 0, stream>>>(x, g1, s1, h1);

  // fused QKV (256^2 8-phase): [4096,2048] x [6144,2048]^T -> scatter q/k/v
  gemm256<0><<<384, 512, 0, stream>>>(h1, wqkvT, 6144, 2048, qb, nullptr);

  // V -> V^T per (b,h)
  vtrans<<<dim3(4, 64, 32), 256, 0, stream>>>(vb, vtb);

  // attention (1D grid: bh in low 5 bits -> XCD-pinned; longest qt first)
  attn_kernel<<<1024, 256, 0, stream>>>(qb, kb, vtb, ctxb);

  // out proj + residual -> x2 (fp32)
  gemm_bt<1><<<32*16, 256, 0, stream>>>(ctxb, woT, 2048, 2048, x2, x, bo);

  // LN2
  ln_kernel<<<4096, 256, 0, stream>>>(x2, g2, s2, h2);

  // FFN1 (256^2 8-phase) + FFN2 (m97)
  gemm256<2><<<512, 512, 0, stream>>>(h2, w1T, 8192, 2048, ffb, b1);
  gemm_bt<1><<<32*16, 256, 0, stream>>>(ffb, w2T, 2048, 8192, out, x2, b2);

  (void)in_sizes; (void)n_in; (void)out_size; (void)ws_size;
}

// Round 5
// 694.944 us; speedup vs baseline: 1.5165x; 1.5165x over previous
//
#include <hip/hip_runtime.h>
#include <hip/hip_bf16.h>
#include <cstdint>

// ---------------- problem constants ----------------
// B=2, S=2048, D=2048, H=16, HD=128, FF=8192; M = B*S = 4096 rows
constexpr float SCALE_QK = 0.02209708691207961f; // 1/sqrt(2048)  (ref uses 1/sqrt(D))

using short8 = __attribute__((ext_vector_type(8))) short;
using f32x4  = __attribute__((ext_vector_type(4))) float;
using ushort4v = __attribute__((ext_vector_type(4))) ushort;

#define MFMA16(a,b,c) __builtin_amdgcn_mfma_f32_16x16x32_bf16((a),(b),(c),0,0,0)

__device__ __forceinline__ ushort f2bf(float f){
  uint32_t u = __builtin_bit_cast(uint32_t, f);
  u += 0x7fffu + ((u >> 16) & 1u);      // RNE
  return (ushort)(u >> 16);
}

// async global->LDS, 16B per lane; LDS dest is wave-uniform base + lane*16
__device__ __forceinline__ void gload_lds16(const void* g, void* l){
  __builtin_amdgcn_global_load_lds(
      (const __attribute__((address_space(1))) void*)g,
      (__attribute__((address_space(3))) void*)l, 16, 0, 0);
}

// ---------------- LayerNorm: fp32 row -> bf16 row ----------------
__global__ __launch_bounds__(256) void ln_kernel(
    const float* __restrict__ x, const float* __restrict__ g,
    const float* __restrict__ sh, ushort* __restrict__ out){
  const int row = blockIdx.x, t = threadIdx.x;
  const float* xr = x + (size_t)row*2048 + t*8;
  float v[8];
  *(float4*)&v[0] = *(const float4*)(xr);
  *(float4*)&v[4] = *(const float4*)(xr + 4);
  float s = 0.f, sq = 0.f;
#pragma unroll
  for (int i = 0; i < 8; ++i){ s += v[i]; sq += v[i]*v[i]; }
#pragma unroll
  for (int d = 1; d < 64; d <<= 1){ s += __shfl_xor(s, d, 64); sq += __shfl_xor(sq, d, 64); }
  __shared__ float red[8];
  const int w = t >> 6, lane = t & 63;
  if (lane == 0){ red[w] = s; red[4 + w] = sq; }
  __syncthreads();
  s  = red[0] + red[1] + red[2] + red[3];
  sq = red[4] + red[5] + red[6] + red[7];
  const float mean = s * (1.f/2048.f);
  const float inv  = rsqrtf(sq * (1.f/2048.f) - mean*mean + 1e-5f);
  union { ushort u[8]; uint4 v4; } o;
#pragma unroll
  for (int i = 0; i < 8; ++i){
    int j = t*8 + i;
    o.u[i] = f2bf((v[i] - mean) * inv * g[j] + sh[j]);
  }
  *(uint4*)(out + (size_t)row*2048 + t*8) = o.v4;
}

// ---------------- weight convert + transpose: fp32 [K][N] -> bf16 [N][K] ----------------
__global__ __launch_bounds__(256) void wconv_t(
    const float* __restrict__ in, ushort* __restrict__ out, int K, int N){
  __shared__ ushort tile[32][34];
  const int tx = threadIdx.x & 31, ty = threadIdx.x >> 5;
  const int n0 = blockIdx.x * 32, k0 = blockIdx.y * 32;
#pragma unroll
  for (int r = 0; r < 4; ++r){
    int kk = ty + r*8;
    tile[kk][tx] = f2bf(in[(size_t)(k0 + kk)*N + n0 + tx]);
  }
  __syncthreads();
#pragma unroll
  for (int r = 0; r < 4; ++r){
    int nn = ty + r*8;
    out[(size_t)(n0 + nn)*K + k0 + tx] = tile[tx][nn];
  }
}

// ---------------- 128x128 m97-structure GEMM ----------------
// EPI 0: fused-QKV scatter (q,k -> [b,h,s,d]; V -> V^T [b,h,d,s] directly);
// EPI 1: fp32 = resid + bias + acc;  EPI 2: bf16 = gelu_tanh(acc + bias)
template<int EPI>
__global__ __launch_bounds__(256) void gemm_bt(
    const ushort* __restrict__ A, const ushort* __restrict__ Bt,
    int N, int K, void* __restrict__ outp,
    const float* __restrict__ resid, const float* __restrict__ bias){
  __shared__ ushort lds[2][128*64];
  const int tid = threadIdx.x, lane = tid & 63, wid = tid >> 6;
  const int wr = wid >> 1, wc = wid & 1;
  const int l15 = lane & 15, l4 = lane >> 4;

  const int bid = blockIdx.x;
  const int xcd = bid & 7, j = bid >> 3;
  const int mb = xcd*4 + (j & 3);
  const int nb = j >> 2;
  const int m0 = mb * 128, n0 = nb * 128;

  f32x4 acc[4][4];
#pragma unroll
  for (int mi = 0; mi < 4; ++mi)
#pragma unroll
    for (int ni = 0; ni < 4; ++ni) acc[mi][ni] = (f32x4){0.f,0.f,0.f,0.f};

  const ushort* Abase = A  + (size_t)m0*K;
  const ushort* Bbase = Bt + (size_t)n0*K;

  const int NTk = K >> 6;
  for (int kt = 0; kt < NTk; ++kt){
    if (kt) __syncthreads();
#pragma unroll
    for (int i = 0; i < 4; ++i){
      const int chunk = (i*4 + wid)*64 + lane;
      const int row = chunk >> 3;
      const int c8  = (chunk & 7) ^ (row & 7);
      const size_t goff = (size_t)row*K + (size_t)kt*64 + c8*8;
      gload_lds16(Abase + goff, (ushort*)&lds[0][0] + (size_t)(i*4 + wid)*512);
      gload_lds16(Bbase + goff, (ushort*)&lds[1][0] + (size_t)(i*4 + wid)*512);
    }
    __syncthreads();

#pragma unroll
    for (int kk = 0; kk < 2; ++kk){
      short8 af[4], bf[4];
      const int kb = kk*4 + l4;
#pragma unroll
      for (int i = 0; i < 4; ++i){
        const int rA = wr*64 + i*16 + l15;
        af[i] = *(const short8*)&lds[0][rA*64 + ((kb ^ (rA & 7))*8)];
        const int rB = wc*64 + i*16 + l15;
        bf[i] = *(const short8*)&lds[1][rB*64 + ((kb ^ (rB & 7))*8)];
      }
#pragma unroll
      for (int mi = 0; mi < 4; ++mi)
#pragma unroll
        for (int ni = 0; ni < 4; ++ni)
          acc[mi][ni] = MFMA16(af[mi], bf[ni], acc[mi][ni]);
    }
  }

#pragma unroll
  for (int mi = 0; mi < 4; ++mi){
#pragma unroll
    for (int ni = 0; ni < 4; ++ni){
      const int rloc = wr*64 + mi*16 + l4*4;
      const int col  = n0 + wc*64 + ni*16 + l15;
      if constexpr (EPI == 0){
        const int which = col >> 11, rest = col & 2047;
        const int h = rest >> 7, d = rest & 127;
        const int mrow = m0 + rloc;
        const int b = mrow >> 11, s = mrow & 2047;
        if (which == 2){
          // V^T write: [bh][d][s], 4 consecutive s per lane -> one 8B store
          ushort4v o;
#pragma unroll
          for (int j2 = 0; j2 < 4; ++j2) o[j2] = f2bf(acc[mi][ni][j2]);
          *(ushort4v*)&((ushort*)outp)[(size_t)2*8388608 +
              (size_t)(b*16 + h)*262144 + (size_t)d*2048 + s] = o;
        } else {
#pragma unroll
          for (int j2 = 0; j2 < 4; ++j2)
            ((ushort*)outp)[(size_t)which*8388608 +
                (((size_t)(b*16 + h)*2048 + (s + j2)) << 7) + d] = f2bf(acc[mi][ni][j2]);
        }
      } else {
#pragma unroll
        for (int j2 = 0; j2 < 4; ++j2){
          const int m = m0 + rloc + j2;
          float v = acc[mi][ni][j2];
          if constexpr (EPI == 1){
            ((float*)outp)[(size_t)m*N + col] = resid[(size_t)m*N + col] + bias[col] + v;
          } else {
            const float xx = v + bias[col];
            const float z  = 0.7978845608f*(xx + 0.044715f*xx*xx*xx);
            const float t  = __expf(-2.f*fabsf(z));
            const float th = (1.f - t)/(1.f + t);
            const float gl = 0.5f*xx*(1.f + copysignf(th, xx));
            ((ushort*)outp)[(size_t)m*N + col] = f2bf(gl);
          }
        }
      }
    }
  }
}

// ---------------- causal flash attention, QBLK=128 ----------------
// grid 512 = 16 qt x 32 bh; id&31 = bh -> XCD = bh&7 (K/V of 4 bh = L2-resident);
// r = id>>5, qt = r<8 ? 15-r : r-8  (blocks id, id+256 land on the same CU and
// their tile-iter counts sum to a constant 36 -> balanced).
// 256 thr = 4 waves; wave w owns 32 q rows (qt*128 + w*32 ..). KV tiles of 64:
// K[64][128] and V^T[128][64] double-buffered in LDS via global_load_lds
// (pre-swizzled source); P per-wave LDS. 80KB LDS -> 2 blocks/CU.
__global__ __launch_bounds__(256, 2) void attn_kernel(
    const ushort* __restrict__ q, const ushort* __restrict__ k,
    const ushort* __restrict__ vt, ushort* __restrict__ ctx){
  __shared__ ushort k_lds[2][64*128];   // 32 KB
  __shared__ ushort v_lds[2][128*64];   // 32 KB  [d][kv]
  __shared__ ushort p_lds[4][32*64];    // 16 KB  per-wave P
  const int tid = threadIdx.x, lane = tid & 63, w = tid >> 6;
  const int l15 = lane & 15, l4 = lane >> 4;
  const int id = blockIdx.x;
  const int bh = id & 31;
  const int r  = id >> 5;
  const int qt = (r < 8) ? (15 - r) : (r - 8);
  const int bb = bh >> 4, hh = bh & 15;
  const ushort* kbase = k  + (size_t)bh * 262144;
  const ushort* vbase = vt + (size_t)bh * 262144;

  // Q fragments: wave w rows qt*128 + w*32 + mi*16 + l15
  short8 qf[2][4];
#pragma unroll
  for (int mi = 0; mi < 2; ++mi){
    const int s = qt*128 + w*32 + mi*16 + l15;
    const ushort* qr = q + ((size_t)bh*2048 + s)*128 + l4*8;
#pragma unroll
    for (int kk = 0; kk < 4; ++kk) qf[mi][kk] = *(const short8*)(qr + kk*32);
  }

  f32x4 cacc[2][8];
#pragma unroll
  for (int mi = 0; mi < 2; ++mi)
#pragma unroll
    for (int dt = 0; dt < 8; ++dt) cacc[mi][dt] = (f32x4){0.f,0.f,0.f,0.f};
  float mrun[2][4], lrun[2][4];
#pragma unroll
  for (int mi = 0; mi < 2; ++mi)
#pragma unroll
    for (int j = 0; j < 4; ++j){ mrun[mi][j] = -1e30f; lrun[mi][j] = 0.f; }

  // stage K tile (64 rows x 128) + V^T tile (128 rows x 64), swizzled slots
  auto stage = [&](int buf, int t){
    const ushort* ksrc = kbase + (size_t)t*8192;
#pragma unroll
    for (int i = 0; i < 4; ++i){
      const int base = i*256 + w*64;
      const int chunk = base + lane;
      const int kr = chunk >> 4;
      const int c8 = (chunk & 15) ^ (kr & 7);
      gload_lds16(ksrc + (size_t)kr*128 + c8*8, &k_lds[buf][(size_t)base*8]);
    }
#pragma unroll
    for (int i = 0; i < 4; ++i){
      const int base = i*256 + w*64;
      const int chunk = base + lane;
      const int vr = chunk >> 3;
      const int c8 = (chunk & 7) ^ (vr & 7);
      gload_lds16(vbase + (size_t)vr*2048 + t*64 + c8*8, &v_lds[buf][(size_t)base*8]);
    }
  };

  const int nt = 2*qt + 2;
  stage(0, 0);
  __syncthreads();
  int cur = 0;
  for (int t = 0; t < nt; ++t){
    if (t + 1 < nt) stage(cur ^ 1, t + 1);   // async prefetch next K/V tile

    // QK^T: sa[mi][ct], scores[32 q][64 kv]
    f32x4 sa[2][4];
#pragma unroll
    for (int mi = 0; mi < 2; ++mi)
#pragma unroll
      for (int ct = 0; ct < 4; ++ct) sa[mi][ct] = (f32x4){0.f,0.f,0.f,0.f};
    __builtin_amdgcn_s_setprio(1);
#pragma unroll
    for (int kk = 0; kk < 4; ++kk){
#pragma unroll
      for (int ct = 0; ct < 4; ++ct){
        const int kr = ct*16 + l15;
        short8 kf = *(const short8*)&k_lds[cur][kr*128 + (((kk*4 + l4) ^ (kr & 7))*8)];
        sa[0][ct] = MFMA16(qf[0][kk], kf, sa[0][ct]);
        sa[1][ct] = MFMA16(qf[1][kk], kf, sa[1][ct]);
      }
    }
    __builtin_amdgcn_s_setprio(0);

    // online softmax (row = mi*16 + l4*4 + j, col = ct*16 + l15)
    const bool diag = (t >= 2*qt);
#pragma unroll
    for (int mi = 0; mi < 2; ++mi){
#pragma unroll
      for (int j = 0; j < 4; ++j){
        const int qa = qt*128 + w*32 + mi*16 + l4*4 + j;
        float mnew = mrun[mi][j];
#pragma unroll
        for (int ct = 0; ct < 4; ++ct){
          float sc = sa[mi][ct][j] * SCALE_QK;
          if (diag){
            const int ka = t*64 + ct*16 + l15;
            sc = (ka > qa) ? -1e30f : sc;
          }
          sa[mi][ct][j] = sc;
          mnew = fmaxf(mnew, sc);
        }
#pragma unroll
        for (int d = 1; d < 16; d <<= 1) mnew = fmaxf(mnew, __shfl_xor(mnew, d, 16));
        const float corr = __expf(mrun[mi][j] - mnew);
        mrun[mi][j] = mnew; lrun[mi][j] *= corr;
        float psum = 0.f;
#pragma unroll
        for (int ct = 0; ct < 4; ++ct){
          const float p = __expf(sa[mi][ct][j] - mnew);
          sa[mi][ct][j] = p; psum += p;
        }
        lrun[mi][j] += psum;
#pragma unroll
        for (int dt = 0; dt < 8; ++dt) cacc[mi][dt][j] *= corr;
      }
    }

    // P -> bf16 LDS (wave-private, no barrier), [row 32][kv 64] swizzled
#pragma unroll
    for (int mi = 0; mi < 2; ++mi)
#pragma unroll
      for (int ct = 0; ct < 4; ++ct)
#pragma unroll
        for (int j = 0; j < 4; ++j){
          const int row = mi*16 + l4*4 + j, col = ct*16 + l15;
          p_lds[w][row*64 + ((col >> 3) ^ (row & 7))*8 + (col & 7)] = f2bf(sa[mi][ct][j]);
        }

    // PV: ctx[32][128] += P[32][64] * V[64][128] (V^T frags from LDS)
    __builtin_amdgcn_s_setprio(1);
#pragma unroll
    for (int kk2 = 0; kk2 < 2; ++kk2){
      const int kb = kk2*4 + l4;
      short8 pa0 = *(const short8*)&p_lds[w][l15*64 + ((kb ^ (l15 & 7))*8)];
      short8 pa1 = *(const short8*)&p_lds[w][(16 + l15)*64 + ((kb ^ (l15 & 7))*8)];
#pragma unroll
      for (int dt = 0; dt < 8; ++dt){
        const int vr = dt*16 + l15;
        short8 vf = *(const short8*)&v_lds[cur][vr*64 + ((kb ^ (vr & 7))*8)];
        cacc[0][dt] = MFMA16(pa0, vf, cacc[0][dt]);
        cacc[1][dt] = MFMA16(pa1, vf, cacc[1][dt]);
      }
    }
    __builtin_amdgcn_s_setprio(0);

    if (t + 1 < nt){ __syncthreads(); cur ^= 1; }
  }

  // epilogue: divide by row sums, write ctx[(b*2048+s)][h*128+d]
#pragma unroll
  for (int mi = 0; mi < 2; ++mi){
    float inv[4];
#pragma unroll
    for (int j = 0; j < 4; ++j){
      float lt = lrun[mi][j];
#pragma unroll
      for (int d = 1; d < 16; d <<= 1) lt += __shfl_xor(lt, d, 16);
      inv[j] = 1.f / lt;
    }
#pragma unroll
    for (int dt = 0; dt < 8; ++dt)
#pragma unroll
      for (int j = 0; j < 4; ++j){
        const int s = qt*128 + w*32 + mi*16 + l4*4 + j;
        const int d = dt*16 + l15;
        ctx[((size_t)(bb*2048 + s))*2048 + hh*128 + d] = f2bf(cacc[mi][dt][j] * inv[j]);
      }
  }
}

// ---------------- launch ----------------
extern "C" void kernel_launch(void* const* d_in, const int* in_sizes, int n_in,
                              void* d_out, int out_size, void* d_ws, size_t ws_size,
                              hipStream_t stream) {
  const float* x  = (const float*)d_in[0];
  const float* wq = (const float*)d_in[1];
  const float* wk = (const float*)d_in[2];
  const float* wv = (const float*)d_in[3];
  const float* wo = (const float*)d_in[4];
  const float* bo = (const float*)d_in[5];
  const float* g1 = (const float*)d_in[6];
  const float* s1 = (const float*)d_in[7];
  const float* g2 = (const float*)d_in[8];
  const float* s2 = (const float*)d_in[9];
  const float* w1 = (const float*)d_in[10];
  const float* b1 = (const float*)d_in[11];
  const float* w2 = (const float*)d_in[12];
  const float* b2 = (const float*)d_in[13];
  float* out = (float*)d_out;
  char* ws = (char*)d_ws;

  // workspace layout (bytes)
  ushort* wqkvT = (ushort*)(ws + 0);         // [6144][2048] bf16 (wq|wk|wv transposed)
  ushort* wkT = (ushort*)(ws + 8388608);
  ushort* wvT = (ushort*)(ws + 16777216);
  ushort* woT = (ushort*)(ws + 25165824);
  ushort* w1T = (ushort*)(ws + 33554432);    // [8192][2048]
  ushort* w2T = (ushort*)(ws + 67108864);    // [2048][8192]
  ushort* h1  = (ushort*)(ws + 100663296);   // [4096][2048]
  ushort* qb  = (ushort*)(ws + 117440512);   // [32][2048][128]; k, v^T follow
  ushort* kb  = (ushort*)(ws + 134217728);   // [32][2048][128]
  ushort* vtb = (ushort*)(ws + 150994944);   // [32][128][2048] (V^T, written by QKV epi)
  ushort* ctxb= (ushort*)(ws + 184549376);   // [4096][2048]
  float*  x2  = (float*)(ws + 201326592);    // [4096][2048] fp32
  ushort* h2  = (ushort*)(ws + 234881024);   // [4096][2048]
  ushort* ffb = (ushort*)(ws + 117440512);   // [4096][8192] aliases q/k/vt (dead after attn)

  // weights -> bf16 transposed
  wconv_t<<<dim3(64, 64), 256, 0, stream>>>(wq, wqkvT, 2048, 2048);
  wconv_t<<<dim3(64, 64), 256, 0, stream>>>(wk, wkT, 2048, 2048);
  wconv_t<<<dim3(64, 64), 256, 0, stream>>>(wv, wvT, 2048, 2048);
  wconv_t<<<dim3(64, 64), 256, 0, stream>>>(wo, woT, 2048, 2048);
  wconv_t<<<dim3(256, 64), 256, 0, stream>>>(w1, w1T, 2048, 8192);
  wconv_t<<<dim3(64, 256), 256, 0, stream>>>(w2, w2T, 8192, 2048);

  // LN1
  ln_kernel<<<4096, 256, 0, stream>>>(x, g1, s1, h1);

  // fused QKV: [4096,2048] x [6144,2048]^T -> q/k [b,h,s,d], V -> V^T [b,h,d,s]
  gemm_bt<0><<<32*48, 256, 0, stream>>>(h1, wqkvT, 6144, 2048, qb, nullptr, nullptr);

  // attention (QBLK=128; XCD-pinned bh; work-paired qt order)
  attn_kernel<<<512, 256, 0, stream>>>(qb, kb, vtb, ctxb);

  // out proj + residual -> x2 (fp32)
  gemm_bt<1><<<32*16, 256, 0, stream>>>(ctxb, woT, 2048, 2048, x2, x, bo);

  // LN2
  ln_kernel<<<4096, 256, 0, stream>>>(x2, g2, s2, h2);

  // FFN
  gemm_bt<2><<<32*64, 256, 0, stream>>>(h2, w1T, 8192, 2048, ffb, nullptr, b1);
  gemm_bt<1><<<32*16, 256, 0, stream>>>(ffb, w2T, 2048, 8192, out, x2, b2);

  (void)in_sizes; (void)n_in; (void)out_size; (void)ws_size;
}